// Round 1
// baseline (2022.129 us; speedup 1.0000x reference)
//
#include <hip/hip_runtime.h>

#define N_NODES 50000
#define IN_DIM  3000
#define HID     512
#define LAT     30
#define N_EDGES 800000
#define M_PAD   50048   // 391*128
#define K1_PAD  3008    // 94*32
#define N4_PAD  3072    // 24*128

typedef __bf16 bf16;
typedef unsigned short u16;
typedef unsigned int uint;
typedef __attribute__((ext_vector_type(4))) float f32x4;
typedef __attribute__((ext_vector_type(8))) bf16 bf16x8;

__device__ __forceinline__ float bf2f(bf16 b){ return (float)b; }

// ---------------- W1 prep: transpose+pad to bf16 ----------------
// W1T[n][k] (k-contig, K1_PAD) = W1[k][n], zero-pad k>=IN_DIM
__global__ void k_w1t(const float* __restrict__ W1, bf16* __restrict__ W1T){
  int k = blockIdx.x*256 + threadIdx.x;
  int n = blockIdx.y;
  if (k >= K1_PAD) return;
  float v = (k < IN_DIM) ? W1[(long)k*HID + n] : 0.f;
  W1T[(long)n*K1_PAD + k] = (bf16)v;
}
// W1P[n][k] = W1[n][k] bf16, zero-pad n>=IN_DIM (rows to N4_PAD)
__global__ void k_w1p(const float* __restrict__ W1, bf16* __restrict__ W1P){
  int k = blockIdx.x*256 + threadIdx.x;
  int n = blockIdx.y;
  if (k >= HID) return;
  float v = (n < IN_DIM) ? W1[(long)n*HID + k] : 0.f;
  W1P[(long)n*HID + k] = (bf16)v;
}

// ---------------- GEMM: C[M][N] = A[M][K] * B^T  (B stored [N][K] bf16) ----
// A either fp32 (inline cvt, row/k guards) or bf16 (rows pre-padded).
template<bool A_FP32, bool C_F32>
__global__ __launch_bounds__(256) void gemm_bt(
    const void* __restrict__ Ap, const bf16* __restrict__ B,
    void* __restrict__ Cp,
    int M, int Kreal, int Ksteps, int A_ld, int B_ld, int Ncols, int C_ld)
{
  __shared__ bf16 Alds[128*32];
  __shared__ bf16 Blds[128*32];
  const int tid  = threadIdx.x;
  const int lane = tid & 63;
  const int w    = tid >> 6;
  const int wm   = (w >> 1) * 64, wn = (w & 1) * 64;
  const int row0 = blockIdx.x * 128, col0 = blockIdx.y * 128;

  f32x4 acc[4][4];
  #pragma unroll
  for (int mi=0;mi<4;mi++)
    #pragma unroll
    for (int ni=0;ni<4;ni++)
      acc[mi][ni] = (f32x4){0.f,0.f,0.f,0.f};

  const int srow = tid >> 1;        // 0..127 staging row
  const int skb  = (tid & 1) * 16;  // 0 or 16

  for (int ks = 0; ks < Ksteps; ks++) {
    const int k0 = ks * 32;
    uint4 aq0, aq1, bq0, bq1;
    { // B stage (always bf16, fully padded)
      const bf16* bsrc = B + (long)(col0 + srow) * B_ld + k0 + skb;
      bq0 = *(const uint4*)bsrc;
      bq1 = *(const uint4*)(bsrc + 8);
    }
    if (A_FP32) {
      const float* A = (const float*)Ap;
      const bool rok = (row0 + srow) < M;
      const long rbase = (long)(row0 + srow) * A_ld;
      bf16x8 av0, av1;
      #pragma unroll
      for (int q = 0; q < 4; q++) {
        int kk = k0 + skb + q*4;
        float4 xv = make_float4(0.f,0.f,0.f,0.f);
        if (rok && kk < Kreal) xv = *(const float4*)(A + rbase + kk);
        if (q < 2) { av0[q*4+0]=(bf16)xv.x; av0[q*4+1]=(bf16)xv.y; av0[q*4+2]=(bf16)xv.z; av0[q*4+3]=(bf16)xv.w; }
        else       { int b=(q-2)*4; av1[b+0]=(bf16)xv.x; av1[b+1]=(bf16)xv.y; av1[b+2]=(bf16)xv.z; av1[b+3]=(bf16)xv.w; }
      }
      aq0 = __builtin_bit_cast(uint4, av0);
      aq1 = __builtin_bit_cast(uint4, av1);
    } else {
      const bf16* asrc = (const bf16*)Ap + (long)(row0 + srow) * A_ld + k0 + skb;
      aq0 = *(const uint4*)asrc;
      aq1 = *(const uint4*)(asrc + 8);
    }
    __syncthreads();
    *(uint4*)&Alds[srow*32 + skb]     = aq0;
    *(uint4*)&Alds[srow*32 + skb + 8] = aq1;
    *(uint4*)&Blds[srow*32 + skb]     = bq0;
    *(uint4*)&Blds[srow*32 + skb + 8] = bq1;
    __syncthreads();

    bf16x8 af[4], bfr[4];
    #pragma unroll
    for (int mi=0;mi<4;mi++)
      af[mi] = *(const bf16x8*)&Alds[(wm + mi*16 + (lane & 15))*32 + (lane>>4)*8];
    #pragma unroll
    for (int ni=0;ni<4;ni++)
      bfr[ni] = *(const bf16x8*)&Blds[(wn + ni*16 + (lane & 15))*32 + (lane>>4)*8];
    #pragma unroll
    for (int mi=0;mi<4;mi++)
      #pragma unroll
      for (int ni=0;ni<4;ni++)
        acc[mi][ni] = __builtin_amdgcn_mfma_f32_16x16x32_bf16(af[mi], bfr[ni], acc[mi][ni], 0, 0, 0);
  }

  const int crb  = (lane >> 4) * 4;
  const int ccol = lane & 15;
  #pragma unroll
  for (int mi=0;mi<4;mi++){
    #pragma unroll
    for (int v=0;v<4;v++){
      int r = row0 + wm + mi*16 + crb + v;
      if (r >= M) continue;
      #pragma unroll
      for (int ni=0;ni<4;ni++){
        int c = col0 + wn + ni*16 + ccol;
        if (c >= Ncols) continue;
        float val = acc[mi][ni][v];
        if (C_F32) ((float*)Cp)[(long)r*C_ld + c] = val;
        else       ((bf16*)Cp)[(long)r*C_ld + c] = (bf16)val;
      }
    }
  }
}

// ---------------- attention dot products: a_src/a_dst = h1 @ att ----------
__global__ void k_attdots(const bf16* __restrict__ h1, const float* __restrict__ att_s,
                          const float* __restrict__ att_d, float* __restrict__ a_src,
                          float* __restrict__ a_dst){
  int gid = blockIdx.x * blockDim.x + threadIdx.x;
  int row = gid >> 6, lane = gid & 63;
  if (row >= N_NODES) return;
  bf16x8 hv = *(const bf16x8*)(h1 + (long)row*HID + lane*8);
  float s1 = 0.f, s2 = 0.f;
  #pragma unroll
  for (int j=0;j<8;j++){
    float h = bf2f(hv[j]);
    s1 = fmaf(h, att_s[lane*8+j], s1);
    s2 = fmaf(h, att_d[lane*8+j], s2);
  }
  #pragma unroll
  for (int o=32;o>0;o>>=1){ s1 += __shfl_down(s1,o); s2 += __shfl_down(s2,o); }
  if (lane == 0){ a_src[row] = s1; a_dst[row] = s2; }
}

// ---------------- CSR build ----------------
__global__ void k_deg(const int* __restrict__ ei, int* __restrict__ deg){
  int e = blockIdx.x*256 + threadIdx.x;
  if (e >= N_EDGES) return;
  atomicAdd(&deg[ei[N_EDGES + e]], 1);
}

__global__ void k_scan(const int* __restrict__ deg, int* __restrict__ off, int* __restrict__ cur){
  const int n = M_PAD, T = 1024;
  int t = threadIdx.x;
  const int per = (n + T - 1) / T;  // 49
  int s0 = t*per, s1 = min(n, s0+per);
  int sum = 0;
  for (int i=s0;i<s1;i++) sum += deg[i];
  __shared__ int sd[1024];
  sd[t] = sum; __syncthreads();
  for (int o=1;o<T;o<<=1){
    int x = (t>=o) ? sd[t-o] : 0;
    __syncthreads();
    sd[t] += x;
    __syncthreads();
  }
  int run = sd[t] - sum;  // exclusive prefix of this thread's chunk
  for (int i=s0;i<s1;i++){
    off[i] = run; cur[i] = run;
    run += deg[i];
  }
  if (s0 < n && s1 == n) off[n] = run;
}

__global__ void k_fill(const int* __restrict__ ei, int* __restrict__ cur, int* __restrict__ csr_src){
  int e = blockIdx.x*256 + threadIdx.x;
  if (e >= N_EDGES) return;
  int d = ei[N_EDGES + e];
  int pos = atomicAdd(&cur[d], 1);
  csr_src[pos] = ei[e];
}

// ---------------- conv1: segment softmax + aggregation + elu -> x1 bf16 ---
__global__ __launch_bounds__(512) void k_conv1(
    const int* __restrict__ off, const int* __restrict__ csr_src,
    const float* __restrict__ a_src, const float* __restrict__ a_dst,
    const bf16* __restrict__ h1, bf16* __restrict__ x1,
    float* __restrict__ p_edge, float* __restrict__ s_node)
{
  const int i = blockIdx.x;
  const int t = threadIdx.x;
  const int start = off[i];
  const int deg = off[i+1] - start;
  __shared__ float p_sh[512];
  __shared__ int   s_sh[512];
  __shared__ float red[512];

  const float ad = a_dst[i];
  float mloc = -1e30f;
  for (int base=0; base<deg; base+=512){
    int k = base + t;
    if (k < deg){
      float e = a_src[csr_src[start+k]] + ad;
      e = (e > 0.f) ? e : 0.2f*e;
      mloc = fmaxf(mloc, e);
    }
  }
  red[t] = mloc; __syncthreads();
  for (int o=256;o>0;o>>=1){ if (t<o) red[t] = fmaxf(red[t], red[t+o]); __syncthreads(); }
  const float m = red[0];
  __syncthreads();

  float acc = 0.f, ssum = 0.f;
  for (int base=0; base<deg; base+=512){
    int cnt = min(512, deg-base);
    if (t < cnt){
      int s = csr_src[start+base+t];
      float e = a_src[s] + ad;
      e = (e > 0.f) ? e : 0.2f*e;
      float p = __expf(e - m);
      p_sh[t] = p; s_sh[t] = s;
      p_edge[start+base+t] = p;
    }
    __syncthreads();
    for (int k=0;k<cnt;k++){
      float pk = p_sh[k];
      ssum += pk;
      acc = fmaf(pk, bf2f(h1[(long)s_sh[k]*HID + t]), acc);
    }
    __syncthreads();
  }
  float val = acc / (ssum + 1e-16f);
  val = (val > 0.f) ? val : expm1f(val);
  x1[(long)i*HID + t] = (bf16)val;
  if (t == 0) s_node[i] = ssum;
}

// ---------------- x2 = x1 @ W2 (fp32 out to d_out) ----------------
__global__ void k_lin2(const bf16* __restrict__ x1, const float* __restrict__ W2,
                       float* __restrict__ x2){
  int j = threadIdx.x;
  int i = blockIdx.x*8 + threadIdx.y;
  if (i >= N_NODES || j >= LAT) return;
  float acc = 0.f;
  const bf16* xr = x1 + (long)i*HID;
  #pragma unroll 8
  for (int c=0;c<HID;c++) acc = fmaf(bf2f(xr[c]), W2[c*LAT + j], acc);
  x2[(long)i*LAT + j] = acc;
}

// ------- conv3: agg3p = segsum(p*x2[src])/s ; x3 = elu(agg3p @ W2^T) bf16 --
__global__ __launch_bounds__(64) void k_conv3(
    const int* __restrict__ off, const int* __restrict__ csr_src,
    const float* __restrict__ p_edge, const float* __restrict__ s_node,
    const float* __restrict__ x2, const float* __restrict__ W2,
    bf16* __restrict__ x3)
{
  const int i = blockIdx.x;
  const int lane = threadIdx.x;
  if (i >= N_NODES){
    #pragma unroll
    for (int r=0;r<8;r++) x3[(long)i*HID + r*64 + lane] = (bf16)0.f;
    return;
  }
  const int start = off[i];
  const int deg = off[i+1] - start;
  float acc = 0.f;
  for (int k=0;k<deg;k++){
    int s = csr_src[start+k];
    float pk = p_edge[start+k];
    if (lane < LAT) acc = fmaf(pk, x2[(long)s*LAT + lane], acc);
  }
  __shared__ float agg[LAT];
  float inv = 1.f/(s_node[i] + 1e-16f);
  if (lane < LAT) agg[lane] = acc * inv;
  __syncthreads();
  #pragma unroll
  for (int r=0;r<8;r++){
    int c = r*64 + lane;
    float v = 0.f;
    #pragma unroll
    for (int j=0;j<LAT;j++) v = fmaf(agg[j], W2[c*LAT + j], v);
    v = (v > 0.f) ? v : expm1f(v);
    x3[(long)i*HID + c] = (bf16)v;
  }
}

// ---------------- launch ----------------
extern "C" void kernel_launch(void* const* d_in, const int* in_sizes, int n_in,
                              void* d_out, int out_size, void* d_ws, size_t ws_size,
                              hipStream_t stream)
{
  const float* x     = (const float*)d_in[0];
  const int*   ei    = (const int*)d_in[1];
  const float* W1    = (const float*)d_in[2];
  const float* W2    = (const float*)d_in[3];
  const float* att_s = (const float*)d_in[4];
  const float* att_d = (const float*)d_in[5];

  float* out_x2 = (float*)d_out;                        // [N,30]
  float* out_x4 = (float*)d_out + (long)N_NODES*LAT;    // [N,3000]

  // big transient scratch inside the (not-yet-written) x4 region of d_out
  bf16* h1 = (bf16*)out_x4;                       // M_PAD*512 bf16 = 51.2 MB
  bf16* x1 = (bf16*)out_x4 + (long)M_PAD*HID;     // next 51.2 MB

  char* w = (char*)d_ws;
  bf16* W1T = (bf16*)w;  w += (long)HID*K1_PAD*2;     // 3.08 MB
  bf16* W1P = (bf16*)w;  w += (long)N4_PAD*HID*2;     // 3.15 MB
  bf16* x3  = (bf16*)w;  w += (long)M_PAD*HID*2;      // 51.2 MB
  int* deg  = (int*)w;   w += (long)M_PAD*4;
  int* offs = (int*)w;   w += (long)(M_PAD+64)*4;
  int* cur  = (int*)w;   w += (long)M_PAD*4;
  int* csr  = (int*)w;   w += (long)N_EDGES*4;
  float* p_e = (float*)w; w += (long)N_EDGES*4;
  float* s_n = (float*)w; w += (long)M_PAD*4;
  float* a_s = (float*)w; w += (long)M_PAD*4;
  float* a_d = (float*)w; w += (long)M_PAD*4;

  k_w1t<<<dim3((K1_PAD+255)/256, HID), 256, 0, stream>>>(W1, W1T);
  k_w1p<<<dim3((HID+255)/256, N4_PAD), 256, 0, stream>>>(W1, W1P);

  // h1 = x @ W1   (bf16 out)
  gemm_bt<true,false><<<dim3(M_PAD/128, HID/128), 256, 0, stream>>>(
      x, W1T, h1, N_NODES, IN_DIM, K1_PAD/32, IN_DIM, K1_PAD, HID, HID);

  k_attdots<<<(N_NODES*64)/256, 256, 0, stream>>>(h1, att_s, att_d, a_s, a_d);

  hipMemsetAsync(deg, 0, (size_t)M_PAD*4, stream);
  k_deg<<<(N_EDGES+255)/256, 256, 0, stream>>>(ei, deg);
  k_scan<<<1, 1024, 0, stream>>>(deg, offs, cur);
  k_fill<<<(N_EDGES+255)/256, 256, 0, stream>>>(ei, cur, csr);

  k_conv1<<<N_NODES, 512, 0, stream>>>(offs, csr, a_s, a_d, h1, x1, p_e, s_n);

  k_lin2<<<dim3((N_NODES+7)/8), dim3(32,8), 0, stream>>>(x1, W2, out_x2);

  k_conv3<<<M_PAD, 64, 0, stream>>>(offs, csr, p_e, s_n, out_x2, W2, x3);

  // x4 = x3 @ W1^T  (fp32 out, overwrites scratch region)
  gemm_bt<false,true><<<dim3(M_PAD/128, N4_PAD/128), 256, 0, stream>>>(
      x3, W1P, out_x4, N_NODES, HID, HID/32, HID, HID, IN_DIM, IN_DIM);
}

// Round 2
// 1334.885 us; speedup vs baseline: 1.5148x; 1.5148x over previous
//
#include <hip/hip_runtime.h>

#define N_NODES 50000
#define IN_DIM  3000
#define HID     512
#define LAT     30
#define N_EDGES 800000
#define M_PAD   50048   // 391*128
#define K1_PAD  3008    // 94*32
#define N4_PAD  3072    // 24*128

typedef __bf16 bf16;
typedef unsigned int uint;
typedef __attribute__((ext_vector_type(4))) float f32x4;
typedef __attribute__((ext_vector_type(8))) bf16 bf16x8;

__device__ __forceinline__ float bf2f(bf16 b){ return (float)b; }

__device__ __forceinline__ void gl16(const void* g, void* l){
  __builtin_amdgcn_global_load_lds(
      (const __attribute__((address_space(1))) void*)g,
      (__attribute__((address_space(3))) void*)l, 16, 0, 0);
}

// ---------------- weight prep ----------------
// W1T[n][k] = W1[k][n], [HID][K1_PAD] bf16, zero-pad k>=IN_DIM
__global__ void k_w1t(const float* __restrict__ W1, bf16* __restrict__ W1T){
  int k = blockIdx.x*256 + threadIdx.x;
  int n = blockIdx.y;
  if (k >= K1_PAD) return;
  float v = (k < IN_DIM) ? W1[(long)k*HID + n] : 0.f;
  W1T[(long)n*K1_PAD + k] = (bf16)v;
}
// W1P[n][k] = W1[n][k], [N4_PAD][HID] bf16, zero-pad n>=IN_DIM
__global__ void k_w1p(const float* __restrict__ W1, bf16* __restrict__ W1P){
  int k = blockIdx.x*256 + threadIdx.x;
  int n = blockIdx.y;
  if (k >= HID) return;
  float v = (n < IN_DIM) ? W1[(long)n*HID + k] : 0.f;
  W1P[(long)n*HID + k] = (bf16)v;
}
// W2T[n][k] = W2[k][n], [128][HID] bf16, zero-pad n>=LAT
__global__ void k_w2t(const float* __restrict__ W2, bf16* __restrict__ W2T){
  int k = blockIdx.x*256 + threadIdx.x;
  int n = blockIdx.y;
  if (k >= HID) return;
  float v = (n < LAT) ? W2[(long)k*LAT + n] : 0.f;
  W2T[(long)n*HID + k] = (bf16)v;
}
// W2P[n][k] = W2[n][k], [HID][32] bf16, zero-pad k>=LAT
__global__ void k_w2p(const float* __restrict__ W2, bf16* __restrict__ W2P){
  int t = blockIdx.x*256 + threadIdx.x;
  if (t >= HID*32) return;
  int n = t >> 5, k = t & 31;
  W2P[t] = (bf16)((k < LAT) ? W2[(long)n*LAT + k] : 0.f);
}

// ---------------- x fp32 -> xb bf16, padded [M_PAD][K1_PAD] ----------------
__global__ __launch_bounds__(256) void k_cvt(const float* __restrict__ x, bf16* __restrict__ xb){
  int chunk = blockIdx.x*256 + threadIdx.x;      // 8-elem chunk within row
  int row = blockIdx.y;
  if (chunk >= K1_PAD/8) return;
  int c8 = chunk*8;
  bf16x8 o;
  if (row < N_NODES && c8 + 8 <= IN_DIM){
    float4 v0 = *(const float4*)(x + (long)row*IN_DIM + c8);
    float4 v1 = *(const float4*)(x + (long)row*IN_DIM + c8 + 4);
    o[0]=(bf16)v0.x; o[1]=(bf16)v0.y; o[2]=(bf16)v0.z; o[3]=(bf16)v0.w;
    o[4]=(bf16)v1.x; o[5]=(bf16)v1.y; o[6]=(bf16)v1.z; o[7]=(bf16)v1.w;
  } else {
    #pragma unroll
    for (int j=0;j<8;j++){
      int c = c8 + j;
      float v = (row < N_NODES && c < IN_DIM) ? x[(long)row*IN_DIM + c] : 0.f;
      o[j] = (bf16)v;
    }
  }
  *(bf16x8*)(xb + (long)row*K1_PAD + c8) = o;
}

// ---------------- GEMM (m97 structure): C = A * B^T ----------------
// A [.][lda] bf16 (rows fully valid up to blockIdx.y*128+127)
// B [.][ldb] bf16 (rows fully valid up to blockIdx.x*128+127)
// grid = dim3(NB_N, NB_M)  -- x is the N dimension (A-panel reuse in L2)
template<bool C_F32, bool ELU>
__global__ __launch_bounds__(256) void gemm_glds(
    const bf16* __restrict__ A, const bf16* __restrict__ B, void* __restrict__ Cp,
    int lda, int ldb, int Ksteps, int Mvalid, int Nvalid, int ldc)
{
  __shared__ bf16 Alds[128*32];
  __shared__ bf16 Blds[128*32];
  const int tid  = threadIdx.x;
  const int lane = tid & 63;
  const int w    = tid >> 6;
  const int wm   = (w >> 1) * 64, wn = (w & 1) * 64;
  const int col0 = blockIdx.x * 128, row0 = blockIdx.y * 128;

  f32x4 acc[4][4];
  #pragma unroll
  for (int mi=0;mi<4;mi++)
    #pragma unroll
    for (int ni=0;ni<4;ni++)
      acc[mi][ni] = (f32x4){0.f,0.f,0.f,0.f};

  const int sr = tid >> 2;          // staging row 0..63
  const int sc = (tid & 3) * 16;    // byte col 0..48

  const char* ga = (const char*)(A + (long)(row0 + sr) * lda) + sc;
  const char* gb = (const char*)(B + (long)(col0 + sr) * ldb) + sc;
  char* la = (char*)Alds + sr*64 + sc;
  char* lb = (char*)Blds + sr*64 + sc;
  const long astep = (long)64 * lda * 2;
  const long bstep = (long)64 * ldb * 2;

  for (int ks = 0; ks < Ksteps; ks++){
    const long ko = (long)ks * 64;   // 32 bf16 = 64 bytes along K
    gl16(ga + ko,         la);
    gl16(ga + ko + astep, la + 64*64);
    gl16(gb + ko,         lb);
    gl16(gb + ko + bstep, lb + 64*64);
    __syncthreads();   // drains vmcnt -> LDS tile ready

    bf16x8 af[4], bfr[4];
    #pragma unroll
    for (int mi=0;mi<4;mi++)
      af[mi] = *(const bf16x8*)&Alds[(wm + mi*16 + (lane & 15))*32 + (lane>>4)*8];
    #pragma unroll
    for (int ni=0;ni<4;ni++)
      bfr[ni] = *(const bf16x8*)&Blds[(wn + ni*16 + (lane & 15))*32 + (lane>>4)*8];
    #pragma unroll
    for (int mi=0;mi<4;mi++)
      #pragma unroll
      for (int ni=0;ni<4;ni++)
        acc[mi][ni] = __builtin_amdgcn_mfma_f32_16x16x32_bf16(af[mi], bfr[ni], acc[mi][ni], 0, 0, 0);
    __syncthreads();   // protect LDS before next stage
  }

  const int crb  = (lane >> 4) * 4;
  const int ccol = lane & 15;
  #pragma unroll
  for (int mi=0;mi<4;mi++){
    #pragma unroll
    for (int v=0;v<4;v++){
      int r = row0 + wm + mi*16 + crb + v;
      if (r >= Mvalid) continue;
      #pragma unroll
      for (int ni=0;ni<4;ni++){
        int c = col0 + wn + ni*16 + ccol;
        if (c >= Nvalid) continue;
        float val = acc[mi][ni][v];
        if (ELU) val = (val > 0.f) ? val : expm1f(val);
        if (C_F32) ((float*)Cp)[(long)r*ldc + c] = val;
        else       ((bf16*)Cp)[(long)r*ldc + c] = (bf16)val;
      }
    }
  }
}

// ---------------- attention dots ----------------
__global__ void k_attdots(const bf16* __restrict__ h1, const float* __restrict__ att_s,
                          const float* __restrict__ att_d, float* __restrict__ a_src,
                          float* __restrict__ a_dst){
  int gid = blockIdx.x * blockDim.x + threadIdx.x;
  int row = gid >> 6, lane = gid & 63;
  if (row >= N_NODES) return;
  bf16x8 hv = *(const bf16x8*)(h1 + (long)row*HID + lane*8);
  float s1 = 0.f, s2 = 0.f;
  #pragma unroll
  for (int j=0;j<8;j++){
    float h = bf2f(hv[j]);
    s1 = fmaf(h, att_s[lane*8+j], s1);
    s2 = fmaf(h, att_d[lane*8+j], s2);
  }
  #pragma unroll
  for (int o=32;o>0;o>>=1){ s1 += __shfl_down(s1,o); s2 += __shfl_down(s2,o); }
  if (lane == 0){ a_src[row] = s1; a_dst[row] = s2; }
}

// ---------------- CSR build ----------------
__global__ void k_deg(const int* __restrict__ ei, int* __restrict__ deg){
  int e = blockIdx.x*256 + threadIdx.x;
  if (e >= N_EDGES) return;
  atomicAdd(&deg[ei[N_EDGES + e]], 1);
}

__global__ void k_scan(const int* __restrict__ deg, int* __restrict__ off, int* __restrict__ cur){
  const int n = M_PAD, T = 1024;
  int t = threadIdx.x;
  const int per = (n + T - 1) / T;
  int s0 = t*per, s1 = min(n, s0+per);
  int sum = 0;
  for (int i=s0;i<s1;i++) sum += deg[i];
  __shared__ int sd[1024];
  sd[t] = sum; __syncthreads();
  for (int o=1;o<T;o<<=1){
    int x = (t>=o) ? sd[t-o] : 0;
    __syncthreads();
    sd[t] += x;
    __syncthreads();
  }
  int run = sd[t] - sum;
  for (int i=s0;i<s1;i++){
    off[i] = run; cur[i] = run;
    run += deg[i];
  }
  if (s0 < n && s1 == n) off[n] = run;
}

__global__ void k_fill(const int* __restrict__ ei, int* __restrict__ cur, int* __restrict__ csr_src){
  int e = blockIdx.x*256 + threadIdx.x;
  if (e >= N_EDGES) return;
  int d = ei[N_EDGES + e];
  int pos = atomicAdd(&cur[d], 1);
  csr_src[pos] = ei[e];
}

// ---------------- conv1: segment softmax + aggregation + elu ----------------
__global__ __launch_bounds__(512) void k_conv1(
    const int* __restrict__ off, const int* __restrict__ csr_src,
    const float* __restrict__ a_src, const float* __restrict__ a_dst,
    const bf16* __restrict__ h1, bf16* __restrict__ x1,
    float* __restrict__ p_edge, float* __restrict__ s_node)
{
  const int i = blockIdx.x;
  const int t = threadIdx.x;
  const int start = off[i];
  const int deg = off[i+1] - start;
  __shared__ float p_sh[512];
  __shared__ int   s_sh[512];
  __shared__ float red[512];

  const float ad = a_dst[i];
  float mloc = -1e30f;
  for (int base=0; base<deg; base+=512){
    int k = base + t;
    if (k < deg){
      float e = a_src[csr_src[start+k]] + ad;
      e = (e > 0.f) ? e : 0.2f*e;
      mloc = fmaxf(mloc, e);
    }
  }
  red[t] = mloc; __syncthreads();
  for (int o=256;o>0;o>>=1){ if (t<o) red[t] = fmaxf(red[t], red[t+o]); __syncthreads(); }
  const float m = red[0];
  __syncthreads();

  float acc = 0.f, ssum = 0.f;
  for (int base=0; base<deg; base+=512){
    int cnt = min(512, deg-base);
    if (t < cnt){
      int s = csr_src[start+base+t];
      float e = a_src[s] + ad;
      e = (e > 0.f) ? e : 0.2f*e;
      float p = __expf(e - m);
      p_sh[t] = p; s_sh[t] = s;
      p_edge[start+base+t] = p;
    }
    __syncthreads();
    for (int k=0;k<cnt;k++){
      float pk = p_sh[k];
      ssum += pk;
      acc = fmaf(pk, bf2f(h1[(long)s_sh[k]*HID + t]), acc);
    }
    __syncthreads();
  }
  float val = acc / (ssum + 1e-16f);
  val = (val > 0.f) ? val : expm1f(val);
  x1[(long)i*HID + t] = (bf16)val;
  if (t == 0) s_node[i] = ssum;
}

// ---------------- conv3 aggregate: aggb = segsum(p*x2[src])/s, bf16 [M_PAD][32] ----
__global__ void k_agg3(const int* __restrict__ off, const int* __restrict__ csr_src,
                       const float* __restrict__ p_edge, const float* __restrict__ s_node,
                       const float* __restrict__ x2, bf16* __restrict__ aggb)
{
  int i = blockIdx.x*8 + (threadIdx.x >> 5);
  int lane = threadIdx.x & 31;
  if (i >= M_PAD) return;
  float acc = 0.f;
  if (i < N_NODES){
    int s0 = off[i], d = off[i+1] - s0;
    for (int k=0;k<d;k++){
      int s = csr_src[s0+k];
      float pk = p_edge[s0+k];
      if (lane < LAT) acc = fmaf(pk, x2[(long)s*LAT + lane], acc);
    }
    acc *= 1.f/(s_node[i] + 1e-16f);
  }
  aggb[(long)i*32 + lane] = (bf16)((lane < LAT) ? acc : 0.f);
}

// ---------------- launch ----------------
extern "C" void kernel_launch(void* const* d_in, const int* in_sizes, int n_in,
                              void* d_out, int out_size, void* d_ws, size_t ws_size,
                              hipStream_t stream)
{
  const float* x     = (const float*)d_in[0];
  const int*   ei    = (const int*)d_in[1];
  const float* W1    = (const float*)d_in[2];
  const float* W2    = (const float*)d_in[3];
  const float* att_s = (const float*)d_in[4];
  const float* att_d = (const float*)d_in[5];

  float* out_x2 = (float*)d_out;                        // [N,30]
  float* out_x4 = (float*)d_out + (long)N_NODES*LAT;    // [N,3000] region (600 MB)

  // transient scratch inside the (not-yet-written) x4 region of d_out
  bf16* xb = (bf16*)out_x4;                             // [M_PAD][K1_PAD] 301 MB
  bf16* h1 = xb + (long)M_PAD*K1_PAD;                   // [M_PAD][HID] 51.2 MB
  bf16* x1 = h1 + (long)M_PAD*HID;                      // [M_PAD][HID] 51.2 MB

  char* w = (char*)d_ws;
  bf16* W1T = (bf16*)w;  w += (long)HID*K1_PAD*2;
  bf16* W1P = (bf16*)w;  w += (long)N4_PAD*HID*2;
  bf16* W2T = (bf16*)w;  w += (long)128*HID*2;
  bf16* W2P = (bf16*)w;  w += (long)HID*32*2;
  bf16* x3  = (bf16*)w;  w += (long)M_PAD*HID*2;
  bf16* aggb= (bf16*)w;  w += (long)M_PAD*32*2;
  int* deg  = (int*)w;   w += (long)M_PAD*4;
  int* offs = (int*)w;   w += (long)(M_PAD+64)*4;
  int* cur  = (int*)w;   w += (long)M_PAD*4;
  int* csr  = (int*)w;   w += (long)N_EDGES*4;
  float* p_e = (float*)w; w += (long)N_EDGES*4;
  float* s_n = (float*)w; w += (long)M_PAD*4;
  float* a_s = (float*)w; w += (long)M_PAD*4;
  float* a_d = (float*)w; w += (long)M_PAD*4;

  // weight prep + input convert
  k_w1t<<<dim3((K1_PAD+255)/256, HID), 256, 0, stream>>>(W1, W1T);
  k_w1p<<<dim3((HID+255)/256, N4_PAD), 256, 0, stream>>>(W1, W1P);
  k_w2t<<<dim3(2, 128), 256, 0, stream>>>(W2, W2T);
  k_w2p<<<(HID*32+255)/256, 256, 0, stream>>>(W2, W2P);
  k_cvt<<<dim3((K1_PAD/8+255)/256, M_PAD), 256, 0, stream>>>(x, xb);

  // CSR build (overlappable with cvt on same stream; cheap anyway)
  hipMemsetAsync(deg, 0, (size_t)M_PAD*4, stream);
  k_deg<<<(N_EDGES+255)/256, 256, 0, stream>>>(ei, deg);
  k_scan<<<1, 1024, 0, stream>>>(deg, offs, cur);
  k_fill<<<(N_EDGES+255)/256, 256, 0, stream>>>(ei, cur, csr);

  // h1 = xb @ W1T^T  [M_PAD][512] bf16
  gemm_glds<false,false><<<dim3(HID/128, M_PAD/128), 256, 0, stream>>>(
      xb, W1T, h1, K1_PAD, K1_PAD, K1_PAD/32, M_PAD, HID, HID);

  k_attdots<<<(N_NODES*64)/256, 256, 0, stream>>>(h1, att_s, att_d, a_s, a_d);

  k_conv1<<<M_PAD, 512, 0, stream>>>(offs, csr, a_s, a_d, h1, x1, p_e, s_n);

  // x2 = x1 @ W2  -> fp32 out (N=30 inside one 128-col block)
  gemm_glds<true,false><<<dim3(1, M_PAD/128), 256, 0, stream>>>(
      x1, W2T, out_x2, HID, HID, HID/32, N_NODES, LAT, LAT);

  // conv3: aggregate on 30-wide x2, then x3 = elu(aggb @ W2P^T) bf16
  k_agg3<<<(M_PAD+7)/8, 256, 0, stream>>>(offs, csr, p_e, s_n, out_x2, aggb);
  gemm_glds<false,true><<<dim3(HID/128, M_PAD/128), 256, 0, stream>>>(
      aggb, W2P, x3, 32, 32, 1, M_PAD, HID, HID);

  // x4 = x3 @ W1P^T -> fp32 out (overwrites xb/h1/x1 scratch)
  gemm_glds<true,false><<<dim3(N4_PAD/128, M_PAD/128), 256, 0, stream>>>(
      x3, W1P, out_x4, HID, HID, HID/32, N_NODES, IN_DIM, IN_DIM);
}